// Round 3
// baseline (638.537 us; speedup 1.0000x reference)
//
#include <hip/hip_runtime.h>
#include <hip/hip_bf16.h>

typedef unsigned short u16;
typedef unsigned int u32;
typedef __attribute__((ext_vector_type(8))) short short8;
typedef __attribute__((ext_vector_type(4))) float f32x4;

#define BATCH 8192
#define FEAT 512
#define DEG 32
#define BM 128
#define BN 128
#define BK 32
#define LDS_STRIDE 40  // 32 + 8 bf16 pad: 16B-aligned rows, spreads banks

__device__ __forceinline__ float b2f(u16 h){
  union { u32 u; float f; } x; x.u = ((u32)h) << 16; return x.f;
}
__device__ __forceinline__ u16 f2b(float f){
  __hip_bfloat16 h = __float2bfloat16(f);
  return *reinterpret_cast<u16*>(&h);
}
__device__ __forceinline__ u32 pack2(float lo, float hi){
  return (u32)f2b(lo) | (((u32)f2b(hi)) << 16);
}

__device__ __forceinline__ f32x4 mfma_bf16_16x16x32(short8 a, short8 b, f32x4 c){
  asm("v_mfma_f32_16x16x32_bf16 %0, %1, %2, %0" : "+v"(c) : "v"(a), "v"(b));
  return c;
}

// ---- gather + mean-pool (f32 in, f32 agg out, bf16 cat=[self|agg] scratch) ----
__global__ __launch_bounds__(256) void gather_agg(
    const float* __restrict__ feat, const int* __restrict__ nodes,
    const int* __restrict__ nidx, float* __restrict__ out_agg,
    u16* __restrict__ cat_bf)
{
  const int b = blockIdx.x;
  const int t = threadIdx.x;
  __shared__ int idx[DEG];
  __shared__ int self_node;
  if (t < DEG) idx[t] = nidx[b * DEG + t];
  if (t == 64) self_node = nodes[b];
  __syncthreads();
  const int f = t * 2;
  float s0 = 0.f, s1 = 0.f;
  #pragma unroll 8
  for (int k = 0; k < DEG; ++k){
    const float2 v = *(const float2*)(feat + (size_t)idx[k] * FEAT + f);
    s0 += v.x; s1 += v.y;
  }
  const float2 sv = *(const float2*)(feat + (size_t)self_node * FEAT + f);
  const float a0 = s0 * (1.f/32.f), a1 = s1 * (1.f/32.f);
  *(float2*)(out_agg + (size_t)b * FEAT + f) = make_float2(a0, a1);
  *(u32*)(cat_bf + (size_t)b * 1024 + f) = pack2(sv.x, sv.y);
  *(u32*)(cat_bf + (size_t)b * 1024 + FEAT + f) = pack2(a0, a1);
}

// ---------------- f32 -> bf16 transpose (out[c][r] = bf16(in[r][c])) --------
__global__ __launch_bounds__(256) void transpose_f2b(
    const float* __restrict__ in, u16* __restrict__ out, int R, int C)
{
  __shared__ float tile[32][33];
  const int c0 = blockIdx.x * 32, r0 = blockIdx.y * 32;
  const int x = threadIdx.x, y = threadIdx.y;
  #pragma unroll
  for (int i = 0; i < 32; i += 8)
    tile[y + i][x] = in[(size_t)(r0 + y + i) * C + (c0 + x)];
  __syncthreads();
  #pragma unroll
  for (int i = 0; i < 32; i += 8)
    out[(size_t)(c0 + y + i) * R + (r0 + x)] = f2b(tile[x][y + i]);
}

// ---------------- GEMM: C[m][n] = sum_k A[m][k] * BT[n][k] ----------------
// MODE 0 (GEMM1): A = cat_bf [m,1024] (bf16). writes raw(f32) + relu(f32).
// MODE 1 (GEMM2): A[m][k] = (32*agg - self)/31 from cat_bf. raw + relu out.
// MODE 2 (GEMM3): A[m][k] = BN-fold(x)*s+t; x = k<512 ? cat_bf agg : gen f32.
template<int MODE>
__global__ __launch_bounds__(256) void gemm_bt(
    const u16* __restrict__ A1, const float* __restrict__ A2f,
    const float* __restrict__ sArr, const float* __restrict__ tArr,
    const u16* __restrict__ BT, int ldb, int K,
    float* __restrict__ Craw, float* __restrict__ Crelu, int ldc)
{
  __shared__ __align__(16) u16 As[BM * LDS_STRIDE];
  __shared__ __align__(16) u16 Bs[BN * LDS_STRIDE];
  const int m0 = blockIdx.y * BM;
  const int n0 = blockIdx.x * BN;
  const int t = threadIdx.x;
  const int wave = t >> 6, lane = t & 63;
  const int wr = wave >> 1, wc = wave & 1;
  const int lm = lane & 15, quad = lane >> 4;

  f32x4 acc[4][4] = {};

  const int arow = t >> 1;            // 0..127
  const int aseg = (t & 1) * 16;      // 0 or 16
  const int m = m0 + arow;

  for (int k0 = 0; k0 < K; k0 += BK){
    const int kk = k0 + aseg;
    u16 buf[16];
    if (MODE == 0){
      const u16* src = A1 + (size_t)m * 1024 + kk;
      *(uint4*)buf = *(const uint4*)src;
      *(uint4*)(buf + 8) = *(const uint4*)(src + 8);
    } else if (MODE == 1){
      const u16* ap = A1 + (size_t)m * 1024 + 512 + kk;  // agg half
      const u16* sp = A1 + (size_t)m * 1024 + kk;        // self half
      u16 ab[16], sb[16];
      *(uint4*)ab = *(const uint4*)ap; *(uint4*)(ab + 8) = *(const uint4*)(ap + 8);
      *(uint4*)sb = *(const uint4*)sp; *(uint4*)(sb + 8) = *(const uint4*)(sp + 8);
      #pragma unroll
      for (int j = 0; j < 16; ++j)
        buf[j] = f2b((32.f * b2f(ab[j]) - b2f(sb[j])) * (1.f/31.f));
    } else {
      float xs[16];
      if (kk < 512){
        const u16* src = A1 + (size_t)m * 1024 + 512 + kk;  // agg (bf16)
        u16 tmp[16];
        *(uint4*)tmp = *(const uint4*)src; *(uint4*)(tmp + 8) = *(const uint4*)(src + 8);
        #pragma unroll
        for (int j = 0; j < 16; ++j) xs[j] = b2f(tmp[j]);
      } else {
        const float4* s4 = (const float4*)(A2f + (size_t)m * 1024 + (kk - 512));
        *(float4*)(xs)      = s4[0];
        *(float4*)(xs + 4)  = s4[1];
        *(float4*)(xs + 8)  = s4[2];
        *(float4*)(xs + 12) = s4[3];
      }
      #pragma unroll
      for (int j = 0; j < 16; ++j)
        buf[j] = f2b(fmaf(xs[j], sArr[kk + j], tArr[kk + j]));
    }
    *(uint4*)&As[arow * LDS_STRIDE + aseg] = *(uint4*)buf;
    *(uint4*)&As[arow * LDS_STRIDE + aseg + 8] = *(uint4*)(buf + 8);
    // ---- stage B tile from BT [N,K] bf16 ----
    {
      const uint4* src = (const uint4*)(BT + (size_t)(n0 + arow) * ldb + kk);
      uint4 v0 = src[0], v1 = src[1];
      *(uint4*)&Bs[arow * LDS_STRIDE + aseg] = v0;
      *(uint4*)&Bs[arow * LDS_STRIDE + aseg + 8] = v1;
    }
    __syncthreads();
    short8 af[4], bf[4];
    #pragma unroll
    for (int i = 0; i < 4; ++i)
      af[i] = *(const short8*)&As[(wr * 64 + i * 16 + lm) * LDS_STRIDE + quad * 8];
    #pragma unroll
    for (int j = 0; j < 4; ++j)
      bf[j] = *(const short8*)&Bs[(wc * 64 + j * 16 + lm) * LDS_STRIDE + quad * 8];
    #pragma unroll
    for (int i = 0; i < 4; ++i)
      #pragma unroll
      for (int j = 0; j < 4; ++j)
        acc[i][j] = mfma_bf16_16x16x32(af[i], bf[j], acc[i][j]);
    __syncthreads();
  }
  // ---- epilogue (f32 out): D row=quad*4+r, col=lm ----
  #pragma unroll
  for (int i = 0; i < 4; ++i){
    const int row = m0 + wr * 64 + i * 16 + quad * 4;
    #pragma unroll
    for (int j = 0; j < 4; ++j){
      const int col = n0 + wc * 64 + j * 16 + lm;
      #pragma unroll
      for (int r = 0; r < 4; ++r){
        const float v = acc[i][j][r];
        const size_t off = (size_t)(row + r) * ldc + col;
        if (MODE != 2){
          Craw[off]  = v;
          Crelu[off] = fmaxf(v, 0.f);
        } else {
          Crelu[off] = fmaxf(v, 0.f);
        }
      }
    }
  }
}

// ---------------- BN stats ----------------
__global__ __launch_bounds__(256) void zero_f32(float* __restrict__ p, int n){
  const int i = blockIdx.x * 256 + threadIdx.x;
  if (i < n) p[i] = 0.f;
}

__global__ __launch_bounds__(256) void bn_partial(
    const u16* __restrict__ cat_bf, const float* __restrict__ gen,
    float* __restrict__ sums)
{
  const int l = threadIdx.x & 63;
  const int ty = threadIdx.x >> 6;            // 0..3
  const int c = blockIdx.x * 64 + l;          // 0..1535
  const int r0 = blockIdx.y * 1024;
  float s = 0.f, q = 0.f;
  if (c < 512){
    for (int r = r0 + ty; r < r0 + 1024; r += 4){
      const float x = b2f(cat_bf[(size_t)r * 1024 + 512 + c]);
      s += x; q += x * x;
    }
  } else {
    for (int r = r0 + ty; r < r0 + 1024; r += 4){
      const float x = gen[(size_t)r * 1024 + (c - 512)];
      s += x; q += x * x;
    }
  }
  __shared__ float sh[2][4][64];
  sh[0][ty][l] = s; sh[1][ty][l] = q;
  __syncthreads();
  if (ty == 0){
    s = sh[0][0][l] + sh[0][1][l] + sh[0][2][l] + sh[0][3][l];
    q = sh[1][0][l] + sh[1][1][l] + sh[1][2][l] + sh[1][3][l];
    atomicAdd(&sums[c], s);
    atomicAdd(&sums[1536 + c], q);
  }
}

__global__ __launch_bounds__(256) void bn_finalize(
    const float* __restrict__ sums, const float* __restrict__ gamma,
    const float* __restrict__ beta, float* __restrict__ sArr, float* __restrict__ tArr)
{
  const int c = blockIdx.x * 256 + threadIdx.x;
  if (c >= 1536) return;
  const float mean = sums[c] * (1.f / 8192.f);
  const float var = sums[1536 + c] * (1.f / 8192.f) - mean * mean;
  const float rs = rsqrtf(var + 1e-5f);
  const float sc = gamma[c] * rs;
  sArr[c] = sc;
  tArr[c] = beta[c] - mean * sc;
}

extern "C" void kernel_launch(void* const* d_in, const int* in_sizes, int n_in,
                              void* d_out, int out_size, void* d_ws, size_t ws_size,
                              hipStream_t stream)
{
  const float* feat  = (const float*)d_in[0];
  const float* Wgen  = (const float*)d_in[1];
  const float* W1    = (const float*)d_in[2];
  const float* gamma = (const float*)d_in[3];
  const float* beta  = (const float*)d_in[4];
  const int* nodes   = (const int*)d_in[5];
  const int* nidx    = (const int*)d_in[6];

  float* o = (float*)d_out;
  float* out_agg    = o;                // [8192,512]
  float* out_to     = o + 4194304;      // [8192,1536]
  float* out_gen    = o + 16777216;     // [8192,1024]
  float* out_raw    = o + 25165824;     // [8192,1024]
  float* out_envgen = o + 33554432;     // [8192,1024]
  float* out_envraw = o + 41943040;     // [8192,1024]

  // ws: 23.6 MB total
  char* w = (char*)d_ws;
  float* sums = (float*)w;                   // 12,288 B
  float* sArr = (float*)(w + 12288);         // 6,144 B
  float* tArr = (float*)(w + 18432);         // 6,144 B
  u16* wgT    = (u16*)(w + 32768);           // 2 MB   [1024,1024] bf16 = W_gen^T
  u16* w1T    = (u16*)(w + 2129920);         // 4.5 MB [1536,1536] bf16 = weight1^T
  u16* cat_bf = (u16*)(w + 6848512);         // 16.8 MB [8192,1024] bf16 [self|agg]
  // end: 23,625,728 bytes

  gather_agg<<<BATCH, 256, 0, stream>>>(feat, nodes, nidx, out_agg, cat_bf);
  transpose_f2b<<<dim3(32, 32), dim3(32, 8), 0, stream>>>(Wgen, wgT, 1024, 1024);
  transpose_f2b<<<dim3(48, 48), dim3(32, 8), 0, stream>>>(W1, w1T, 1536, 1536);

  // GEMM1: raw/gen = cat @ W_gen
  gemm_bt<0><<<dim3(8, 64), 256, 0, stream>>>(
      cat_bf, nullptr, nullptr, nullptr, wgT, 1024, 1024,
      out_raw, out_gen, 1024);
  // GEMM2: env_raw/env_gen = env_agg @ W_gen[512:,:]  (env from cat in staging)
  gemm_bt<1><<<dim3(8, 64), 256, 0, stream>>>(
      cat_bf, nullptr, nullptr, nullptr, wgT + 512, 1024, 512,
      out_envraw, out_envgen, 1024);

  zero_f32<<<12, 256, 0, stream>>>(sums, 3072);
  bn_partial<<<dim3(24, 8), 256, 0, stream>>>(cat_bf, out_gen, sums);
  bn_finalize<<<6, 256, 0, stream>>>(sums, gamma, beta, sArr, tArr);

  // GEMM3: to = relu(BN([agg, gen]) @ weight1), BN folded into A-staging
  gemm_bt<2><<<dim3(12, 64), 256, 0, stream>>>(
      cat_bf, out_gen, sArr, tArr, w1T, 1536, 1536,
      nullptr, out_to, 1536);
}

// Round 4
// 598.879 us; speedup vs baseline: 1.0662x; 1.0662x over previous
//
#include <hip/hip_runtime.h>
#include <hip/hip_bf16.h>

typedef unsigned short u16;
typedef unsigned int u32;
typedef __attribute__((ext_vector_type(8))) short short8;
typedef __attribute__((ext_vector_type(4))) float f32x4;

#define BATCH 8192
#define FEAT 512
#define DEG 32
#define BM 128
#define BN 128
#define BK 32

__device__ __forceinline__ float b2f(u16 h){
  union { u32 u; float f; } x; x.u = ((u32)h) << 16; return x.f;
}
__device__ __forceinline__ u16 f2b(float f){
  __hip_bfloat16 h = __float2bfloat16(f);
  return *reinterpret_cast<u16*>(&h);
}
__device__ __forceinline__ u32 pack2(float lo, float hi){
  return (u32)f2b(lo) | (((u32)f2b(hi)) << 16);
}

__device__ __forceinline__ f32x4 mfma_bf16_16x16x32(short8 a, short8 b, f32x4 c){
  asm("v_mfma_f32_16x16x32_bf16 %0, %1, %2, %0" : "+v"(c) : "v"(a), "v"(b));
  return c;
}

// async global->LDS, 16B per lane; LDS dest = wave-uniform base + lane*16
__device__ __forceinline__ void gload16(const u16* g, u16* l){
  __builtin_amdgcn_global_load_lds(
      (const __attribute__((address_space(1))) u32*)(const void*)g,
      (__attribute__((address_space(3))) u32*)(void*)l, 16, 0, 0);
}

// ---- gather + mean-pool: agg(f32), cat=[self|agg](bf16), env(bf16) ----
__global__ __launch_bounds__(256) void gather_agg(
    const float* __restrict__ feat, const int* __restrict__ nodes,
    const int* __restrict__ nidx, float* __restrict__ out_agg,
    u16* __restrict__ cat_bf, u16* __restrict__ env_bf)
{
  const int b = blockIdx.x;
  const int t = threadIdx.x;
  __shared__ int idx[DEG];
  __shared__ int self_node;
  if (t < DEG) idx[t] = nidx[b * DEG + t];
  if (t == 64) self_node = nodes[b];
  __syncthreads();
  const int f = t * 2;
  float s0 = 0.f, s1 = 0.f;
  #pragma unroll 8
  for (int k = 0; k < DEG; ++k){
    const float2 v = *(const float2*)(feat + (size_t)idx[k] * FEAT + f);
    s0 += v.x; s1 += v.y;
  }
  const float2 sv = *(const float2*)(feat + (size_t)self_node * FEAT + f);
  const float a0 = s0 * (1.f/32.f), a1 = s1 * (1.f/32.f);
  // env removes column 0 == nodes row: (sum - feat[idx[0]])/31; idx[0]==nodes
  const float e0 = (s0 - sv.x) * (1.f/31.f), e1 = (s1 - sv.y) * (1.f/31.f);
  *(float2*)(out_agg + (size_t)b * FEAT + f) = make_float2(a0, a1);
  *(u32*)(cat_bf + (size_t)b * 1024 + f) = pack2(sv.x, sv.y);
  *(u32*)(cat_bf + (size_t)b * 1024 + FEAT + f) = pack2(a0, a1);
  *(u32*)(env_bf + (size_t)b * FEAT + f) = pack2(e0, e1);
}

// ---------------- f32 -> bf16 transpose (out[c][r] = bf16(in[r][c])) --------
__global__ __launch_bounds__(256) void transpose_f2b(
    const float* __restrict__ in, u16* __restrict__ out, int R, int C)
{
  __shared__ float tile[32][33];
  const int c0 = blockIdx.x * 32, r0 = blockIdx.y * 32;
  const int x = threadIdx.x, y = threadIdx.y;
  #pragma unroll
  for (int i = 0; i < 32; i += 8)
    tile[y + i][x] = in[(size_t)(r0 + y + i) * C + (c0 + x)];
  __syncthreads();
  #pragma unroll
  for (int i = 0; i < 32; i += 8)
    out[(size_t)(c0 + y + i) * R + (r0 + x)] = f2b(tile[x][y + i]);
}

// ---- m97-style GEMM body: C[m][n] = sum_k A[m][k]*BT[n][k], bf16 in f32 out ----
template<bool WRITE_RAW>
__device__ __forceinline__ void gemm_body(
    const u16* __restrict__ A, int lda, const u16* __restrict__ BT, int ldb,
    int K, float* __restrict__ Craw, float* __restrict__ Crelu, int ldc,
    int m0, int n0, u16* As, u16* Bs)
{
  const int t = threadIdx.x;
  const int wave = t >> 6, lane = t & 63;
  const int wr = wave >> 1, wc = wave & 1;
  const int lm = lane & 15, quad = lane >> 4;

  // staging coords: wave wv covers rows wv*32+(lane/4) (+16 for 2nd inst), col (lane%4)*8
  const int sr = wave * 32 + (lane >> 2);
  const int sc = (lane & 3) * 8;

  f32x4 acc[4][4] = {};

  for (int k0 = 0; k0 < K; k0 += BK){
    gload16(A  + (size_t)(m0 + sr)      * lda + k0 + sc, As + sr * 32 + sc);
    gload16(A  + (size_t)(m0 + sr + 16) * lda + k0 + sc, As + (sr + 16) * 32 + sc);
    gload16(BT + (size_t)(n0 + sr)      * ldb + k0 + sc, Bs + sr * 32 + sc);
    gload16(BT + (size_t)(n0 + sr + 16) * ldb + k0 + sc, Bs + (sr + 16) * 32 + sc);
    __syncthreads();
    short8 af[4], bf[4];
    #pragma unroll
    for (int i = 0; i < 4; ++i)
      af[i] = *(const short8*)&As[(wr * 64 + i * 16 + lm) * 32 + quad * 8];
    #pragma unroll
    for (int j = 0; j < 4; ++j)
      bf[j] = *(const short8*)&Bs[(wc * 64 + j * 16 + lm) * 32 + quad * 8];
    #pragma unroll
    for (int i = 0; i < 4; ++i)
      #pragma unroll
      for (int j = 0; j < 4; ++j)
        acc[i][j] = mfma_bf16_16x16x32(af[i], bf[j], acc[i][j]);
    __syncthreads();
  }
  #pragma unroll
  for (int i = 0; i < 4; ++i){
    const int row = m0 + wr * 64 + i * 16 + quad * 4;
    #pragma unroll
    for (int j = 0; j < 4; ++j){
      const int col = n0 + wc * 64 + j * 16 + lm;
      #pragma unroll
      for (int r = 0; r < 4; ++r){
        const float v = acc[i][j][r];
        const size_t off = (size_t)(row + r) * ldc + col;
        if (WRITE_RAW) Craw[off] = v;
        Crelu[off] = fmaxf(v, 0.f);
      }
    }
  }
}

// GEMM1 (z=0): cat @ Wgen -> raw, gen.  GEMM2 (z=1): env @ Wgen[512:] -> envraw, envgen.
__global__ __launch_bounds__(256) void gemm12(
    const u16* __restrict__ catA, const u16* __restrict__ envA,
    const u16* __restrict__ wgT,
    float* __restrict__ raw, float* __restrict__ gen,
    float* __restrict__ envraw, float* __restrict__ envgen)
{
  __shared__ __align__(16) u16 As[BM * BK];
  __shared__ __align__(16) u16 Bs[BN * BK];
  const int z = blockIdx.z;
  const u16* A  = z ? envA : catA;
  const int lda = z ? 512 : 1024;
  const int K   = z ? 512 : 1024;
  const u16* BT = z ? wgT + 512 : wgT;
  float* Craw   = z ? envraw : raw;
  float* Crelu  = z ? envgen : gen;
  gemm_body<true>(A, lda, BT, 1024, K, Craw, Crelu, 1024,
                  blockIdx.y * BM, blockIdx.x * BN, As, Bs);
}

// GEMM3: bnA @ weight1 -> relu only
__global__ __launch_bounds__(256) void gemm3(
    const u16* __restrict__ bnA, const u16* __restrict__ w1T,
    float* __restrict__ to_out)
{
  __shared__ __align__(16) u16 As[BM * BK];
  __shared__ __align__(16) u16 Bs[BN * BK];
  gemm_body<false>(bnA, 1536, w1T, 1536, 1536, nullptr, to_out, 1536,
                   blockIdx.y * BM, blockIdx.x * BN, As, Bs);
}

// ---------------- BN stats ----------------
__global__ __launch_bounds__(256) void zero_f32(float* __restrict__ p, int n){
  const int i = blockIdx.x * 256 + threadIdx.x;
  if (i < n) p[i] = 0.f;
}

__global__ __launch_bounds__(256) void bn_partial(
    const float* __restrict__ agg, const float* __restrict__ gen,
    float* __restrict__ sums)
{
  const int l = threadIdx.x & 63;
  const int ty = threadIdx.x >> 6;            // 0..3
  const int c = blockIdx.x * 64 + l;          // 0..1535
  const int r0 = blockIdx.y * 1024;
  float s = 0.f, q = 0.f;
  if (c < 512){
    for (int r = r0 + ty; r < r0 + 1024; r += 4){
      const float x = agg[(size_t)r * 512 + c];
      s += x; q += x * x;
    }
  } else {
    for (int r = r0 + ty; r < r0 + 1024; r += 4){
      const float x = gen[(size_t)r * 1024 + (c - 512)];
      s += x; q += x * x;
    }
  }
  __shared__ float sh[2][4][64];
  sh[0][ty][l] = s; sh[1][ty][l] = q;
  __syncthreads();
  if (ty == 0){
    s = sh[0][0][l] + sh[0][1][l] + sh[0][2][l] + sh[0][3][l];
    q = sh[1][0][l] + sh[1][1][l] + sh[1][2][l] + sh[1][3][l];
    atomicAdd(&sums[c], s);
    atomicAdd(&sums[1536 + c], q);
  }
}

__global__ __launch_bounds__(256) void bn_finalize(
    const float* __restrict__ sums, const float* __restrict__ gamma,
    const float* __restrict__ beta, float* __restrict__ sArr, float* __restrict__ tArr)
{
  const int c = blockIdx.x * 256 + threadIdx.x;
  if (c >= 1536) return;
  const float mean = sums[c] * (1.f / 8192.f);
  const float var = sums[1536 + c] * (1.f / 8192.f) - mean * mean;
  const float rs = rsqrtf(var + 1e-5f);
  const float sc = gamma[c] * rs;
  sArr[c] = sc;
  tArr[c] = beta[c] - mean * sc;
}

// ---- materialize BN-folded GEMM3 A-matrix: bnA[m][c] = bf16(x*s + t) ----
__global__ __launch_bounds__(384) void prep_bnA(
    const float* __restrict__ agg, const float* __restrict__ gen,
    const float* __restrict__ sArr, const float* __restrict__ tArr,
    u16* __restrict__ bnA)
{
  const int m = blockIdx.x;
  const int t = threadIdx.x;       // 0..383
  const int c = t * 4;
  const float4 x = (c < 512)
      ? *(const float4*)(agg + (size_t)m * 512 + c)
      : *(const float4*)(gen + (size_t)m * 1024 + (c - 512));
  const float4 s4 = *(const float4*)(sArr + c);
  const float4 t4 = *(const float4*)(tArr + c);
  const u32 lo = pack2(fmaf(x.x, s4.x, t4.x), fmaf(x.y, s4.y, t4.y));
  const u32 hi = pack2(fmaf(x.z, s4.z, t4.z), fmaf(x.w, s4.w, t4.w));
  *(uint2*)(bnA + (size_t)m * 1536 + c) = make_uint2(lo, hi);
}

extern "C" void kernel_launch(void* const* d_in, const int* in_sizes, int n_in,
                              void* d_out, int out_size, void* d_ws, size_t ws_size,
                              hipStream_t stream)
{
  const float* feat  = (const float*)d_in[0];
  const float* Wgen  = (const float*)d_in[1];
  const float* W1    = (const float*)d_in[2];
  const float* gamma = (const float*)d_in[3];
  const float* beta  = (const float*)d_in[4];
  const int* nodes   = (const int*)d_in[5];
  const int* nidx    = (const int*)d_in[6];

  float* o = (float*)d_out;
  float* out_agg    = o;                // [8192,512]
  float* out_to     = o + 4194304;      // [8192,1536]
  float* out_gen    = o + 16777216;     // [8192,1024]
  float* out_raw    = o + 25165824;     // [8192,1024]
  float* out_envgen = o + 33554432;     // [8192,1024]
  float* out_envraw = o + 41943040;     // [8192,1024]

  // ws: 30.5 MB; bnA overlays cat+env (dead after gemm12)
  char* w = (char*)d_ws;
  float* sums = (float*)w;                   // 12,288 B
  float* sArr = (float*)(w + 12288);         // 6,144 B
  float* tArr = (float*)(w + 18432);         // 6,144 B
  u16* wgT    = (u16*)(w + 32768);           // 2 MB    [1024,1024] bf16 W_gen^T
  u16* w1T    = (u16*)(w + 2129920);         // 4.5 MB  [1536,1536] bf16 weight1^T
  u16* cat_bf = (u16*)(w + 6848512);         // 16.8 MB [8192,1024] bf16 [self|agg]
  u16* env_bf = (u16*)(w + 23625728);        // 8.4 MB  [8192,512]  bf16 env
  u16* bnA_bf = (u16*)(w + 6848512);         // 25.2 MB [8192,1536] overlay
  // end: 32,014,336 bytes

  gather_agg<<<BATCH, 256, 0, stream>>>(feat, nodes, nidx, out_agg, cat_bf, env_bf);
  transpose_f2b<<<dim3(32, 32), dim3(32, 8), 0, stream>>>(Wgen, wgT, 1024, 1024);
  transpose_f2b<<<dim3(48, 48), dim3(32, 8), 0, stream>>>(W1, w1T, 1536, 1536);

  // GEMM1+GEMM2 fused across blockIdx.z (1024 blocks -> 4/CU)
  gemm12<<<dim3(8, 64, 2), 256, 0, stream>>>(
      cat_bf, env_bf, wgT, out_raw, out_gen, out_envraw, out_envgen);

  zero_f32<<<12, 256, 0, stream>>>(sums, 3072);
  bn_partial<<<dim3(24, 8), 256, 0, stream>>>(out_agg, out_gen, sums);
  bn_finalize<<<6, 256, 0, stream>>>(sums, gamma, beta, sArr, tArr);
  prep_bnA<<<BATCH, 384, 0, stream>>>(out_agg, out_gen, sArr, tArr, bnA_bf);

  gemm3<<<dim3(12, 64), 256, 0, stream>>>(bnA_bf, w1T, out_to);
}